// Round 1
// baseline (1009.296 us; speedup 1.0000x reference)
//
#include <hip/hip_runtime.h>

typedef unsigned short u16;
typedef float f32x4 __attribute__((ext_vector_type(4)));
typedef u16   u16x8 __attribute__((ext_vector_type(8)));
typedef short s16x8 __attribute__((ext_vector_type(8)));

__device__ __forceinline__ u16 f2bf(float f) {
  // round-to-nearest-even fp32 -> bf16 (finite inputs)
  unsigned u = __builtin_bit_cast(unsigned, f);
  unsigned r = (u + 0x7fffu + ((u >> 16) & 1u)) >> 16;
  return (u16)r;
}

// ---------------- K1: B = A * A^T (fp32, 64x64 tiles, transposed LDS staging) ----------------
__global__ __launch_bounds__(256) void k_bbt(const float* __restrict__ A, float* __restrict__ B) {
  __shared__ float Ai[32][68];
  __shared__ float Aj[32][68];
  const int tid = threadIdx.x;
  const int i0 = blockIdx.y * 64, j0 = blockIdx.x * 64;
  const int tx = tid & 15, ty = tid >> 4;
  const int sr = tid >> 2;          // 0..63 tile row
  const int sc = (tid & 3) * 8;     // 0,8,16,24
  f32x4 acc[4];
#pragma unroll
  for (int q = 0; q < 4; ++q) acc[q] = {0.f, 0.f, 0.f, 0.f};

  for (int k0 = 0; k0 < 1024; k0 += 32) {
    f32x4 a0 = *(const f32x4*)&A[(size_t)(i0 + sr) * 1024 + k0 + sc];
    f32x4 a1 = *(const f32x4*)&A[(size_t)(i0 + sr) * 1024 + k0 + sc + 4];
    f32x4 b0 = *(const f32x4*)&A[(size_t)(j0 + sr) * 1024 + k0 + sc];
    f32x4 b1 = *(const f32x4*)&A[(size_t)(j0 + sr) * 1024 + k0 + sc + 4];
    __syncthreads();
#pragma unroll
    for (int q = 0; q < 4; ++q) {
      Ai[sc + q][sr] = a0[q]; Ai[sc + 4 + q][sr] = a1[q];
      Aj[sc + q][sr] = b0[q]; Aj[sc + 4 + q][sr] = b1[q];
    }
    __syncthreads();
#pragma unroll
    for (int kk = 0; kk < 32; ++kk) {
      f32x4 av = *(const f32x4*)&Ai[kk][ty * 4];
      f32x4 bv = *(const f32x4*)&Aj[kk][tx * 4];
#pragma unroll
      for (int q = 0; q < 4; ++q) acc[q] += bv * av[q];
    }
  }
#pragma unroll
  for (int q = 0; q < 4; ++q)
    *(f32x4*)&B[(size_t)(i0 + ty * 4 + q) * 1024 + j0 + tx * 4] = acc[q];
}

// ---------------- rd2[i] = 2/diag[i] ----------------
__global__ void k_rd2(const float* __restrict__ B, float* __restrict__ rd2) {
  int i = blockIdx.x * 256 + threadIdx.x;
  if (i < 1024) rd2[i] = 2.0f / B[(size_t)i * 1025];
}

// ---------------- in-block forward substitution (64 rows), column-parallel ----------------
// grid: 16 blocks x 64 threads; block bc owns columns [bc*64, bc*64+64)
__global__ __launch_bounds__(64) void k_solve(const float* __restrict__ B, const float* __restrict__ rd2,
                                              float* __restrict__ P, int k0) {
  __shared__ float coef[64][64];
  const int lane = threadIdx.x;
  const int c = blockIdx.x * 64 + lane;
  const float r2 = rd2[k0 + lane];
  for (int i = 0; i < 64; ++i) {
    float v = B[(size_t)(k0 + i) * 1024 + k0 + lane] * r2;
    coef[i][lane] = (lane > i) ? v : 0.0f;   // coef[i][j]=2*B[k0+i][k0+j]/diag[k0+j]
  }
  float pc[64];
#pragma unroll
  for (int r = 0; r < 64; ++r) pc[r] = P[(size_t)(k0 + r) * 1024 + c];
  __syncthreads();
#pragma unroll
  for (int i = 0; i < 63; ++i) {
    const float pi = pc[i];
#pragma unroll
    for (int j = i + 1; j < 64; ++j) pc[j] -= coef[i][j] * pi;   // static indices: no scratch
  }
#pragma unroll
  for (int r = 0; r < 64; ++r) P[(size_t)(k0 + r) * 1024 + c] = pc[r];
}

// ---------------- trailing update: P[j0.., n0..] -= C[j, blk] @ P[blk, n0..] ----------------
__global__ __launch_bounds__(256) void k_trail(const float* __restrict__ B, const float* __restrict__ rd2,
                                               float* __restrict__ P, int k0) {
  __shared__ float Ct[64][68];   // Ct[jj][i] = B[j][k0+i]*rd2[j]   (B symmetric)
  __shared__ float Pb[64][68];   // Pb[i][nn]
  const int tid = threadIdx.x;
  const int j0 = k0 + 64 + blockIdx.x * 64;
  const int n0 = blockIdx.y * 64;
  const int sr = tid >> 2, sc = (tid & 3) * 16;
  {
    const float r2 = rd2[j0 + sr];
    const float* src = &B[(size_t)(j0 + sr) * 1024 + k0 + sc];
    const float* ps  = &P[(size_t)(k0 + sr) * 1024 + n0 + sc];
#pragma unroll
    for (int q = 0; q < 4; ++q) {
      f32x4 v = *(const f32x4*)(src + q * 4);
      v = v * r2;
      *(f32x4*)&Ct[sr][sc + q * 4] = v;
      *(f32x4*)&Pb[sr][sc + q * 4] = *(const f32x4*)(ps + q * 4);
    }
  }
  __syncthreads();
  const int tx = tid & 15, ty = tid >> 4;
  f32x4 acc[4];
#pragma unroll
  for (int q = 0; q < 4; ++q) acc[q] = {0.f, 0.f, 0.f, 0.f};
#pragma unroll 8
  for (int i = 0; i < 64; ++i) {
    f32x4 pv = *(const f32x4*)&Pb[i][tx * 4];
#pragma unroll
    for (int q = 0; q < 4; ++q) acc[q] += pv * Ct[ty * 4 + q][i];
  }
#pragma unroll
  for (int q = 0; q < 4; ++q) {
    f32x4* dst = (f32x4*)&P[(size_t)(j0 + ty * 4 + q) * 1024 + n0 + tx * 4];
    f32x4 old = *dst;
    *dst = old - acc[q];
  }
}

// ---------------- Wt[n][k] = bf16( delta(k,n) - sum_i A[i][k]*rd2[i]*P[i][n] ) ----------------
__global__ __launch_bounds__(256) void k_w(const float* __restrict__ A, const float* __restrict__ P,
                                           const float* __restrict__ rd2, u16* __restrict__ Wt) {
  __shared__ float As[32][68];
  __shared__ float Ps[32][68];
  const int tid = threadIdx.x;
  const int kb = blockIdx.y * 64, nb = blockIdx.x * 64;
  const int sr = tid >> 3, sc = (tid & 7) * 8;
  const int tx = tid & 15, ty = tid >> 4;
  f32x4 acc[4];
#pragma unroll
  for (int q = 0; q < 4; ++q) acc[q] = {0.f, 0.f, 0.f, 0.f};

  for (int i0 = 0; i0 < 1024; i0 += 32) {
    float r2 = rd2[i0 + sr];
    f32x4 a0 = *(const f32x4*)&A[(size_t)(i0 + sr) * 1024 + kb + sc];
    f32x4 a1 = *(const f32x4*)&A[(size_t)(i0 + sr) * 1024 + kb + sc + 4];
    f32x4 p0 = *(const f32x4*)&P[(size_t)(i0 + sr) * 1024 + nb + sc];
    f32x4 p1 = *(const f32x4*)&P[(size_t)(i0 + sr) * 1024 + nb + sc + 4];
    __syncthreads();
    *(f32x4*)&As[sr][sc]     = a0 * r2;
    *(f32x4*)&As[sr][sc + 4] = a1 * r2;
    *(f32x4*)&Ps[sr][sc]     = p0;
    *(f32x4*)&Ps[sr][sc + 4] = p1;
    __syncthreads();
#pragma unroll
    for (int i = 0; i < 32; ++i) {
      f32x4 av = *(const f32x4*)&As[i][ty * 4];
      f32x4 pv = *(const f32x4*)&Ps[i][tx * 4];
#pragma unroll
      for (int q = 0; q < 4; ++q) acc[q] += pv * av[q];
    }
  }
#pragma unroll
  for (int q = 0; q < 4; ++q) {
    int k = kb + ty * 4 + q;
#pragma unroll
    for (int j = 0; j < 4; ++j) {
      int n = nb + tx * 4 + j;
      float w = ((k == n) ? 1.0f : 0.0f) - acc[q][j];
      Wt[(size_t)n * 1024 + k] = f2bf(w);
    }
  }
}

// ---------------- big GEMM: out[M,1024] = x[M,1024] @ W + b  (A: fp32->bf16 reg-staged; B: global_load_lds) ----------------
#define GL_LDS16(gp, lp)                                                     \
  __builtin_amdgcn_global_load_lds((const __attribute__((address_space(1))) void*)(gp), \
                                   (__attribute__((address_space(3))) void*)(lp), 16, 0, 0)

__global__ __launch_bounds__(256) void k_out(const float* __restrict__ X, const u16* __restrict__ Wt,
                                             const float* __restrict__ bvec, float* __restrict__ out) {
  __shared__ u16 As[128 * 32];   // bf16 [128 rows][32 k]
  __shared__ u16 Bs[128 * 32];   // bf16 [128 n-rows][32 k]
  const int tid = threadIdx.x;
  const int lane = tid & 63, wid = tid >> 6;
  const int wr = wid >> 1, wc = wid & 1;          // 2x2 waves of 64x64
  const int ni = blockIdx.x, mi = blockIdx.y;
  const long m0 = (long)mi * 128;
  const int n0 = ni * 128;

  const int arow = tid >> 1, ac = (tid & 1) * 16;
  const float* xbase = X + (m0 + arow) * 1024 + ac;

  const int brow = tid >> 2, bc0 = (tid & 3) * 8;
  const u16* wbase0 = Wt + (size_t)(n0 + brow) * 1024 + bc0;
  const u16* wbase1 = Wt + (size_t)(n0 + 64 + brow) * 1024 + bc0;
  u16* asl  = &As[tid * 16];
  u16* bsl0 = &Bs[tid * 8];
  u16* bsl1 = &Bs[2048 + tid * 8];

  f32x4 acc[4][4];
#pragma unroll
  for (int m = 0; m < 4; ++m)
#pragma unroll
    for (int n = 0; n < 4; ++n) acc[m][n] = {0.f, 0.f, 0.f, 0.f};

  const int aro = (wr * 64 + (lane & 15)) * 32 + (lane >> 4) * 8;
  const int bro = (wc * 64 + (lane & 15)) * 32 + (lane >> 4) * 8;

  for (int k0 = 0; k0 < 1024; k0 += 32) {
    GL_LDS16(wbase0 + k0, bsl0);
    GL_LDS16(wbase1 + k0, bsl1);
    f32x4 x0 = *(const f32x4*)(xbase + k0);
    f32x4 x1 = *(const f32x4*)(xbase + k0 + 4);
    f32x4 x2 = *(const f32x4*)(xbase + k0 + 8);
    f32x4 x3 = *(const f32x4*)(xbase + k0 + 12);
    u16x8 h0, h1;
#pragma unroll
    for (int q = 0; q < 4; ++q) {
      h0[q] = f2bf(x0[q]); h0[4 + q] = f2bf(x1[q]);
      h1[q] = f2bf(x2[q]); h1[4 + q] = f2bf(x3[q]);
    }
    *(u16x8*)(asl)     = h0;
    *(u16x8*)(asl + 8) = h1;
    __syncthreads();   // also drains global_load_lds (vmcnt0) and ds_writes

    s16x8 af[4], bf[4];
#pragma unroll
    for (int m = 0; m < 4; ++m) af[m] = *(const s16x8*)&As[aro + m * 512];
#pragma unroll
    for (int n = 0; n < 4; ++n) bf[n] = *(const s16x8*)&Bs[bro + n * 512];
#pragma unroll
    for (int m = 0; m < 4; ++m)
#pragma unroll
      for (int n = 0; n < 4; ++n)
        acc[m][n] = __builtin_amdgcn_mfma_f32_16x16x32_bf16(af[m], bf[n], acc[m][n], 0, 0, 0);
    __syncthreads();
  }

  const long orow0 = m0 + wr * 64 + (lane >> 4) * 4;
  const int  ocol0 = n0 + wc * 64 + (lane & 15);
#pragma unroll
  for (int n = 0; n < 4; ++n) {
    const int c = ocol0 + n * 16;
    const float bb = bvec[c];
#pragma unroll
    for (int m = 0; m < 4; ++m) {
      const long r = orow0 + m * 16;
#pragma unroll
      for (int q = 0; q < 4; ++q)
        out[(r + q) * 1024 + c] = acc[m][n][q] + bb;
    }
  }
}

extern "C" void kernel_launch(void* const* d_in, const int* in_sizes, int n_in,
                              void* d_out, int out_size, void* d_ws, size_t ws_size,
                              hipStream_t stream) {
  const float* x  = (const float*)d_in[0];
  const float* A  = (const float*)d_in[1];
  const float* bv = (const float*)d_in[2];
  float* out = (float*)d_out;
  char* ws = (char*)d_ws;

  float* B   = (float*)(ws);                      // 4 MB
  float* P   = (float*)(ws + (4u << 20));         // 4 MB
  u16*   Wt  = (u16*)  (ws + (8u << 20));         // 2 MB
  float* rd2 = (float*)(ws + (10u << 20));        // 4 KB

  hipMemcpyAsync(P, A, 1024 * 1024 * sizeof(float), hipMemcpyDeviceToDevice, stream);
  k_bbt<<<dim3(16, 16), 256, 0, stream>>>(A, B);
  k_rd2<<<4, 256, 0, stream>>>(B, rd2);
  for (int k = 0; k < 16; ++k) {
    k_solve<<<16, 64, 0, stream>>>(B, rd2, P, k * 64);
    if (k < 15) k_trail<<<dim3(15 - k, 16), 256, 0, stream>>>(B, rd2, P, k * 64);
  }
  k_w<<<dim3(16, 16), 256, 0, stream>>>(A, P, rd2, Wt);
  k_out<<<dim3(8, 512), 256, 0, stream>>>(x, Wt, bv, out);
}

// Round 2
// 727.957 us; speedup vs baseline: 1.3865x; 1.3865x over previous
//
#include <hip/hip_runtime.h>
#include <hip/hip_bf16.h>

typedef unsigned short u16;
typedef float f32x4 __attribute__((ext_vector_type(4)));
typedef u16   u16x8 __attribute__((ext_vector_type(8)));
typedef u16   u16x4 __attribute__((ext_vector_type(4)));
typedef short s16x8 __attribute__((ext_vector_type(8)));

__device__ __forceinline__ u16 f2bf(float f) {
  unsigned u = __builtin_bit_cast(unsigned, f);
  unsigned r = (u + 0x7fffu + ((u >> 16) & 1u)) >> 16;
  return (u16)r;
}
__device__ __forceinline__ u16 cvtbf(float f) {
  return __builtin_bit_cast(u16, __float2bfloat16(f));
}

// ---------------- K1: B = A * A^T (fp32, 64x64 tiles) ----------------
__global__ __launch_bounds__(256) void k_bbt(const float* __restrict__ A, float* __restrict__ B) {
  __shared__ float Ai[32][68];
  __shared__ float Aj[32][68];
  const int tid = threadIdx.x;
  const int i0 = blockIdx.y * 64, j0 = blockIdx.x * 64;
  const int tx = tid & 15, ty = tid >> 4;
  const int sr = tid >> 2;
  const int sc = (tid & 3) * 8;
  f32x4 acc[4];
#pragma unroll
  for (int q = 0; q < 4; ++q) acc[q] = {0.f, 0.f, 0.f, 0.f};

  for (int k0 = 0; k0 < 1024; k0 += 32) {
    f32x4 a0 = *(const f32x4*)&A[(size_t)(i0 + sr) * 1024 + k0 + sc];
    f32x4 a1 = *(const f32x4*)&A[(size_t)(i0 + sr) * 1024 + k0 + sc + 4];
    f32x4 b0 = *(const f32x4*)&A[(size_t)(j0 + sr) * 1024 + k0 + sc];
    f32x4 b1 = *(const f32x4*)&A[(size_t)(j0 + sr) * 1024 + k0 + sc + 4];
    __syncthreads();
#pragma unroll
    for (int q = 0; q < 4; ++q) {
      Ai[sc + q][sr] = a0[q]; Ai[sc + 4 + q][sr] = a1[q];
      Aj[sc + q][sr] = b0[q]; Aj[sc + 4 + q][sr] = b1[q];
    }
    __syncthreads();
#pragma unroll
    for (int kk = 0; kk < 32; ++kk) {
      f32x4 av = *(const f32x4*)&Ai[kk][ty * 4];
      f32x4 bv = *(const f32x4*)&Aj[kk][tx * 4];
#pragma unroll
      for (int q = 0; q < 4; ++q) acc[q] += bv * av[q];
    }
  }
#pragma unroll
  for (int q = 0; q < 4; ++q)
    *(f32x4*)&B[(size_t)(i0 + ty * 4 + q) * 1024 + j0 + tx * 4] = acc[q];
}

// ---------------- rd2[i] = 2/diag[i] ----------------
__global__ void k_rd2(const float* __restrict__ B, float* __restrict__ rd2) {
  int i = blockIdx.x * 256 + threadIdx.x;
  if (i < 1024) rd2[i] = 2.0f / B[(size_t)i * 1025];
}

// ---------------- fused step k: apply source block (k-1) to rows >= k*64, solve block k ----------------
// grid: dim3(16, 16-k); blockIdx.y==0 -> update-own + solve; y>0 -> trailing update only.
__global__ __launch_bounds__(256) void k_step(const float* __restrict__ B, const float* __restrict__ rd2,
                                              float* __restrict__ P, int k) {
  __shared__ float Ct[64][68];
  __shared__ float Pb[64][68];
  __shared__ float Pu[64][68];
  __shared__ float Cs[64][68];
  const int tid = threadIdx.x;
  const int cb = blockIdx.x, rb = k + blockIdx.y;
  const int n0 = cb * 64;
  const int tx = tid & 15, ty = tid >> 4;
  f32x4 acc[4];
#pragma unroll
  for (int q = 0; q < 4; ++q) acc[q] = {0.f, 0.f, 0.f, 0.f};

  if (k > 0) {
    const int s = k - 1;
    const int sr = tid >> 2, sc = (tid & 3) * 16;
    const float r2 = rd2[rb * 64 + sr];
    const float* bsrc = &B[(size_t)(rb * 64 + sr) * 1024 + s * 64 + sc];
    const float* psrc = &P[(size_t)(s * 64 + sr) * 1024 + n0 + sc];
#pragma unroll
    for (int q = 0; q < 4; ++q) {
      f32x4 v = *(const f32x4*)(bsrc + q * 4);
      *(f32x4*)&Ct[sr][sc + q * 4] = v * r2;
      *(f32x4*)&Pb[sr][sc + q * 4] = *(const f32x4*)(psrc + q * 4);
    }
    __syncthreads();
#pragma unroll 8
    for (int i = 0; i < 64; ++i) {
      f32x4 pv = *(const f32x4*)&Pb[i][tx * 4];
#pragma unroll
      for (int q = 0; q < 4; ++q) acc[q] += pv * Ct[ty * 4 + q][i];
    }
  }

  if (rb == k) {
    if (k > 0) {
#pragma unroll
      for (int q = 0; q < 4; ++q) {
        f32x4 old = *(const f32x4*)&P[(size_t)(k * 64 + ty * 4 + q) * 1024 + n0 + tx * 4];
        *(f32x4*)&Pu[ty * 4 + q][tx * 4] = old - acc[q];
      }
    } else {
      const int sr = tid >> 2, sc = (tid & 3) * 16;
#pragma unroll
      for (int q = 0; q < 4; ++q)
        *(f32x4*)&Pu[sr][sc + q * 4] = *(const f32x4*)&P[(size_t)sr * 1024 + n0 + sc + q * 4];
    }
    {
      const int i = tid >> 2, j0 = (tid & 3) * 16;
      const float* bs = &B[(size_t)(k * 64 + i) * 1024 + k * 64 + j0];
#pragma unroll
      for (int jj = 0; jj < 16; ++jj) {
        int j = j0 + jj;
        Cs[i][j] = (j > i) ? bs[jj] * rd2[k * 64 + j] : 0.0f;
      }
    }
    __syncthreads();
    if (tid < 64) {
      const int c = tid;
      float pc[64];
#pragma unroll
      for (int r = 0; r < 64; ++r) pc[r] = Pu[r][c];
#pragma unroll
      for (int i = 0; i < 63; ++i) {
        const float pi = pc[i];
#pragma unroll
        for (int j = i + 1; j < 64; ++j) pc[j] -= Cs[i][j] * pi;
      }
#pragma unroll
      for (int r = 0; r < 64; ++r) P[(size_t)(k * 64 + r) * 1024 + n0 + c] = pc[r];
    }
  } else {
#pragma unroll
    for (int q = 0; q < 4; ++q) {
      f32x4* dst = (f32x4*)&P[(size_t)(rb * 64 + ty * 4 + q) * 1024 + n0 + tx * 4];
      *dst = *dst - acc[q];
    }
  }
}

// ---------------- Wf in MFMA-B-fragment order ----------------
// element (k,n): offset = ((k>>5)*64 + (n>>4))*512 + (((k>>3)&3)*16 + (n&15))*8 + (k&7)
__global__ __launch_bounds__(256) void k_w(const float* __restrict__ A, const float* __restrict__ P,
                                           const float* __restrict__ rd2, u16* __restrict__ Wf) {
  __shared__ float As[32][68];
  __shared__ float Ps[32][68];
  const int tid = threadIdx.x;
  const int kb = blockIdx.y * 64, nb = blockIdx.x * 64;
  const int sr = tid >> 3, sc = (tid & 7) * 8;
  const int tx = tid & 15, ty = tid >> 4;
  f32x4 acc[4];
#pragma unroll
  for (int q = 0; q < 4; ++q) acc[q] = {0.f, 0.f, 0.f, 0.f};

  for (int i0 = 0; i0 < 1024; i0 += 32) {
    float r2 = rd2[i0 + sr];
    f32x4 a0 = *(const f32x4*)&A[(size_t)(i0 + sr) * 1024 + kb + sc];
    f32x4 a1 = *(const f32x4*)&A[(size_t)(i0 + sr) * 1024 + kb + sc + 4];
    f32x4 p0 = *(const f32x4*)&P[(size_t)(i0 + sr) * 1024 + nb + sc];
    f32x4 p1 = *(const f32x4*)&P[(size_t)(i0 + sr) * 1024 + nb + sc + 4];
    __syncthreads();
    *(f32x4*)&As[sr][sc]     = a0 * r2;
    *(f32x4*)&As[sr][sc + 4] = a1 * r2;
    *(f32x4*)&Ps[sr][sc]     = p0;
    *(f32x4*)&Ps[sr][sc + 4] = p1;
    __syncthreads();
#pragma unroll
    for (int i = 0; i < 32; ++i) {
      f32x4 av = *(const f32x4*)&As[i][ty * 4];
      f32x4 pv = *(const f32x4*)&Ps[i][tx * 4];
#pragma unroll
      for (int q = 0; q < 4; ++q) acc[q] += pv * av[q];
    }
  }
  const int ktile = (kb + ty * 4) >> 5;
  const int kg = ((ty * 4) >> 3) & 3;
  const int e0 = (ty * 4) & 7;           // 0 or 4
#pragma unroll
  for (int j = 0; j < 4; ++j) {
    int n = nb + tx * 4 + j;
    int nt = n >> 4;
    int ln = kg * 16 + (n & 15);
    u16x4 pk;
#pragma unroll
    for (int q = 0; q < 4; ++q) {
      int kk = kb + ty * 4 + q;
      float w = ((kk == n) ? 1.0f : 0.0f) - acc[q][j];
      pk[q] = f2bf(w);
    }
    *(u16x4*)&Wf[((size_t)(ktile * 64 + nt) * 64 + ln) * 8 + e0] = pk;
  }
}

// ---------------- big GEMM: out = x @ W + b ----------------
#define GL_LDS16(gp, lp)                                                     \
  __builtin_amdgcn_global_load_lds((const __attribute__((address_space(1))) void*)(gp), \
                                   (__attribute__((address_space(3))) void*)(lp), 16, 0, 0)

__global__ __launch_bounds__(256) void k_out(const float* __restrict__ X, const u16* __restrict__ Wf,
                                             const float* __restrict__ bvec, float* __restrict__ out) {
  __shared__ u16 As[8192];   // fragment-order [kt2][msub][lane][8]
  __shared__ u16 Bs[8192];   // fragment-order [kt2][nsub][lane][8]
  const int tid = threadIdx.x;
  const int lane = tid & 63, wid = tid >> 6;
  const int wr = wid >> 1, wc = wid & 1;
  const int lin = blockIdx.x;
  const int mi = (lin & 7) * 64 + (lin >> 6);      // XCD-chunked: each XCD owns 64 consecutive mi
  const int ni = (lin >> 3) & 7;
  const long m0 = (long)mi * 128;
  const int n0 = ni * 128;

  // A-staging precompute: pass j handles element chunk c = j*256+tid -> row m=c>>3, col-group kg8=c&7
  const float *xs0, *xs1, *xs2, *xs3;
  int aw0, aw1, aw2, aw3;
#define APREP(J, XS, AW) { int c = (J) * 256 + tid; int m = c >> 3, kg8 = c & 7;       \
    XS = X + (m0 + m) * 1024 + kg8 * 8;                                                \
    int kt2 = kg8 >> 2, ks = kg8 & 3, msub = m >> 4, mm = m & 15;                      \
    AW = (((kt2 * 8 + msub) * 64 + ks * 16 + mm) * 16) ^ (ks << 4); }
  APREP(0, xs0, aw0) APREP(1, xs1, aw1) APREP(2, xs2, aw2) APREP(3, xs3, aw3)
#undef APREP

  const u16* wsrc0 = Wf + (size_t)ni * 4096 + tid * 8;
  u16* bd0 = Bs + tid * 8;

  const int aro = (lane * 16) ^ (((lane >> 4) & 3) << 4);   // matches write-side XOR
  const char* Ab = (const char*)As + aro;
  const char* Bb = (const char*)Bs + lane * 16;

  f32x4 acc[4][4];
#pragma unroll
  for (int m = 0; m < 4; ++m)
#pragma unroll
    for (int n = 0; n < 4; ++n) acc[m][n] = {0.f, 0.f, 0.f, 0.f};

  for (int it = 0; it < 16; ++it) {
    const u16* w0 = wsrc0 + (size_t)it * 65536;
    GL_LDS16(w0,          bd0);
    GL_LDS16(w0 + 2048,   bd0 + 2048);
    GL_LDS16(w0 + 32768,  bd0 + 4096);
    GL_LDS16(w0 + 34816,  bd0 + 6144);
    const int ko = it * 64;
#define ASTAGE(XS, AW) { f32x4 u = *(const f32x4*)((XS) + ko); f32x4 v = *(const f32x4*)((XS) + ko + 4); \
    u16x8 h;                                                                              \
    h[0] = cvtbf(u[0]); h[1] = cvtbf(u[1]); h[2] = cvtbf(u[2]); h[3] = cvtbf(u[3]);       \
    h[4] = cvtbf(v[0]); h[5] = cvtbf(v[1]); h[6] = cvtbf(v[2]); h[7] = cvtbf(v[3]);       \
    *(u16x8*)((char*)As + (AW)) = h; }
    ASTAGE(xs0, aw0) ASTAGE(xs1, aw1) ASTAGE(xs2, aw2) ASTAGE(xs3, aw3)
#undef ASTAGE
    __syncthreads();
#pragma unroll
    for (int kt2 = 0; kt2 < 2; ++kt2) {
      s16x8 af[4], bfr[4];
#pragma unroll
      for (int m = 0; m < 4; ++m) af[m] = *(const s16x8*)(Ab + ((kt2 * 8 + wr * 4 + m) << 10));
#pragma unroll
      for (int n = 0; n < 4; ++n) bfr[n] = *(const s16x8*)(Bb + ((kt2 * 8 + wc * 4 + n) << 10));
#pragma unroll
      for (int m = 0; m < 4; ++m)
#pragma unroll
        for (int n = 0; n < 4; ++n)
          acc[m][n] = __builtin_amdgcn_mfma_f32_16x16x32_bf16(af[m], bfr[n], acc[m][n], 0, 0, 0);
    }
    __syncthreads();
  }

  const long orow0 = m0 + wr * 64 + (lane >> 4) * 4;
  const int  ocol0 = n0 + wc * 64 + (lane & 15);
#pragma unroll
  for (int n = 0; n < 4; ++n) {
    const int cc = ocol0 + n * 16;
    const float bb = bvec[cc];
#pragma unroll
    for (int m = 0; m < 4; ++m) {
      const long r = orow0 + m * 16;
#pragma unroll
      for (int q = 0; q < 4; ++q)
        out[(r + q) * 1024 + cc] = acc[m][n][q] + bb;
    }
  }
}

extern "C" void kernel_launch(void* const* d_in, const int* in_sizes, int n_in,
                              void* d_out, int out_size, void* d_ws, size_t ws_size,
                              hipStream_t stream) {
  const float* x  = (const float*)d_in[0];
  const float* A  = (const float*)d_in[1];
  const float* bv = (const float*)d_in[2];
  float* out = (float*)d_out;
  char* ws = (char*)d_ws;

  float* B   = (float*)(ws);                      // 4 MB
  float* P   = (float*)(ws + (4u << 20));         // 4 MB
  u16*   Wf  = (u16*)  (ws + (8u << 20));         // 2 MB (fragment-order W)
  float* rd2 = (float*)(ws + (10u << 20));        // 4 KB

  hipMemcpyAsync(P, A, 1024 * 1024 * sizeof(float), hipMemcpyDeviceToDevice, stream);
  k_bbt<<<dim3(16, 16), 256, 0, stream>>>(A, B);
  k_rd2<<<4, 256, 0, stream>>>(B, rd2);
  for (int k = 0; k < 16; ++k)
    k_step<<<dim3(16, 16 - k), 256, 0, stream>>>(B, rd2, P, k);
  k_w<<<dim3(16, 16), 256, 0, stream>>>(A, P, rd2, Wf);
  k_out<<<4096, 256, 0, stream>>>(x, Wf, bv, out);
}